// Round 12
// baseline (194.913 us; speedup 1.0000x reference)
//
#include <hip/hip_runtime.h>
#include <math.h>
#include <stdint.h>

#define B 4
#define T 8192
#define D 512
#define NN 256
#define L 768
#define TE 2048
#define H 8
#define DH 64
#define MR 64
#define AS 520          // Abuf row stride (bf16 elems)
#define SLICE 16384     // elems per 32-K staged B slice (512 cols * 32 k)

typedef __bf16 bf16;
typedef bf16  bf16x8 __attribute__((ext_vector_type(8)));
typedef float f32x4  __attribute__((ext_vector_type(4)));

__device__ __forceinline__ float sigmoidf_(float x){ return 1.0f/(1.0f+__expf(-x)); }

// ======== k_prep: kv only (unchanged from r10) ========
__global__ __launch_bounds__(256) void k_prep(
    const float* __restrict__ xf, const float* __restrict__ Wk,
    const float* __restrict__ bk, const float* __restrict__ Wv,
    const float* __restrict__ bv, const float* __restrict__ tg,
    const float* __restrict__ tb, bf16* __restrict__ kbuf, bf16* __restrict__ vbuf){
    __shared__ float xfn[8][L];
    const int bid = blockIdx.x, t = threadIdx.x;
    int g0 = (bid >> 2) * 8, jc = bid & 3;
    int wave = t >> 6, lane = t & 63;
    #pragma unroll
    for (int rr = 0; rr < 2; ++rr){
        int r = wave*2 + rr, g = g0 + r;
        float vals[12];
        float s = 0.f, sq = 0.f;
        #pragma unroll
        for (int i = 0; i < 12; ++i){ float v = xf[(size_t)g*L + lane*12 + i]; vals[i] = v; s += v; sq += v*v; }
        #pragma unroll
        for (int o = 32; o; o >>= 1){ s += __shfl_xor(s, o); sq += __shfl_xor(sq, o); }
        float m = s / L; float var = sq / L - m*m;
        float rstd = rsqrtf(var + 1e-5f);
        #pragma unroll
        for (int i = 0; i < 12; ++i){
            int l = lane*12 + i;
            xfn[r][l] = (vals[i]-m)*rstd*tg[l] + tb[l];
        }
    }
    __syncthreads();
    const float* Wm = (t < 128) ? Wk : Wv;
    int col = jc*128 + (t & 127);
    float acc[8];
    #pragma unroll
    for (int r = 0; r < 8; ++r) acc[r] = 0.f;
    for (int l = 0; l < L; l += 4){
        float4 xv[8];
        #pragma unroll
        for (int r = 0; r < 8; ++r) xv[r] = *(const float4*)&xfn[r][l];
        #pragma unroll
        for (int u = 0; u < 4; ++u){
            float wv = Wm[(size_t)(l+u)*D + col];
            #pragma unroll
            for (int r = 0; r < 8; ++r) acc[r] += ((const float*)&xv[r])[u] * wv;
        }
    }
    float bias = (t < 128) ? bk[col] : bv[col];
    bf16* dst = (t < 128) ? kbuf : vbuf;
    #pragma unroll
    for (int r = 0; r < 8; ++r){
        size_t g = (size_t)(g0 + r);
        dst[g*D + col] = (bf16)(acc[r] + bias);
    }
}

// ======== k_att2: attn state + weight re-layout + ss (unchanged from r10) ========
__global__ __launch_bounds__(256) void k_att2(
    const bf16* __restrict__ kbuf, const bf16* __restrict__ vbuf, bf16* __restrict__ attF,
    const float* __restrict__ Wq, const float* __restrict__ oW,
    bf16* __restrict__ wqS, bf16* __restrict__ owS,
    const float* __restrict__ emb, const float* __restrict__ emb_W,
    const float* __restrict__ emb_b, float* __restrict__ ss){
    __shared__ __align__(16) char smem[133120];
    const int bid = blockIdx.x, t = threadIdx.x;
    if (bid < 32){
        float* kh = (float*)smem;
        float* vh = kh + NN*DH;
        float (*pm)[DH] = (float(*)[DH])(vh + NN*DH);
        float (*ps)[DH] = pm + 4;
        int h = bid & 7, b = bid >> 3;
        for (int k = 0; k < NN*DH/256; ++k){
            int m = k*256 + t;
            int n = m >> 6, dl = m & 63;
            size_t src = (size_t)(b*NN + n)*D + h*DH + dl;
            kh[m] = (float)kbuf[src]; vh[m] = (float)vbuf[src];
        }
        __syncthreads();
        int d = t & 63, c = t >> 6;
        float mx = -1e30f;
        for (int n = c*64; n < c*64+64; ++n) mx = fmaxf(mx, kh[n*DH + d]);
        pm[c][d] = mx;
        __syncthreads();
        mx = fmaxf(fmaxf(pm[0][d], pm[1][d]), fmaxf(pm[2][d], pm[3][d]));
        float s = 0.f;
        for (int n = c*64; n < c*64+64; ++n){ float e = __expf(kh[n*DH + d] - mx); kh[n*DH + d] = e; s += e; }
        ps[c][d] = s;
        __syncthreads();
        float inv = 1.f/(ps[0][d] + ps[1][d] + ps[2][d] + ps[3][d]);
        for (int n = c*64; n < c*64+64; ++n) kh[n*DH + d] *= inv;
        __syncthreads();
        int l = t >> 2, dd0 = (t & 3)*16;
        float acc[16];
        #pragma unroll
        for (int i = 0; i < 16; ++i) acc[i] = 0.f;
        for (int n = 0; n < NN; ++n){
            float vv = vh[n*DH + l];
            #pragma unroll
            for (int i = 0; i < 16; ++i) acc[i] += kh[n*DH + dd0 + i] * vv;
        }
        size_t hbase = ((size_t)(b*H + h)) << 12;
        #pragma unroll
        for (int half = 0; half < 2; ++half){
            int d0 = dd0 + half*8;
            int f  = (l >> 4)*2 + (d0 >> 5);
            int ln = ((d0 >> 3) & 3)*16 + (l & 15);
            bf16x8 ov;
            #pragma unroll
            for (int j = 0; j < 8; ++j) ov[j] = (bf16)acc[half*8 + j];
            *(bf16x8*)&attF[hbase + f*512 + ln*8] = ov;
        }
    } else if (bid < 160){
        int lb2 = bid - 32;
        const float* W = (lb2 < 64) ? Wq : oW;
        bf16* Wst = (lb2 < 64) ? wqS : owS;
        int lb = lb2 & 63;
        int k0 = (lb & 7)*64, n0 = (lb >> 3)*64;
        float (*tile)[65] = (float(*)[65])smem;
        int c = t & 63, r4 = t >> 6;
        #pragma unroll
        for (int p = 0; p < 16; ++p){ int r = p*4 + r4; tile[r][c] = W[(size_t)(k0+r)*D + n0 + c]; }
        __syncthreads();
        int oct = t >> 6, col = t & 63;
        #pragma unroll
        for (int half = 0; half < 2; ++half){
            int kk = (lb & 7)*2 + half;
            bf16x8 ov;
            #pragma unroll
            for (int j = 0; j < 8; ++j) ov[j] = (bf16)tile[half*32 + oct*8 + j][col];
            *(bf16x8*)&Wst[(size_t)kk*SLICE + (n0+col)*32 + oct*8] = ov;
        }
    } else {
        float (*semb)[TE] = (float(*)[TE])smem;
        float (*red)[64]  = (float(*)[64])(smem + 4*TE*4);
        int c = bid - 160;
        for (int i = t; i < TE; i += 256)
            #pragma unroll
            for (int b = 0; b < B; ++b){ float e = emb[b*TE + i]; semb[b][i] = e * sigmoidf_(e); }
        __syncthreads();
        int o = t & 15, p = t >> 4;
        int j = c*16 + o;
        float acc[B] = {0.f,0.f,0.f,0.f};
        for (int i = 0; i < 128; ++i){
            int e = p*128 + i;
            float wv = emb_W[(size_t)e*1024 + j];
            #pragma unroll
            for (int b = 0; b < B; ++b) acc[b] += semb[b][e] * wv;
        }
        #pragma unroll
        for (int b = 0; b < B; ++b) red[p][b*16 + o] = acc[b];
        __syncthreads();
        if (t < 64){
            int b = t >> 4, o2 = t & 15;
            int j2 = c*16 + o2;
            float s = 0.f;
            #pragma unroll
            for (int pp = 0; pp < 16; ++pp) s += red[pp][b*16 + o2];
            ss[b*1024 + j2] = s + emb_b[j2];
        }
    }
}

// ======== rolled, register-double-buffered GEMM over K=512 (+T5 setprio) ========
__device__ __forceinline__ void gemm_body(const bf16* __restrict__ wfrag,
                                          const bf16* __restrict__ afrag,
                                          f32x4 (&acc)[4][4]){
    bf16x8 b0[4], b1[4];
    #pragma unroll
    for (int nt = 0; nt < 4; ++nt) b0[nt] = *(const bf16x8*)&wfrag[nt*512];
    #pragma unroll
    for (int nt = 0; nt < 4; ++nt) b1[nt] = *(const bf16x8*)&wfrag[SLICE + nt*512];
    const bf16* wp = wfrag + 2*(size_t)SLICE;
    const bf16* ap = afrag;
    __builtin_amdgcn_s_setprio(1);
    for (int kk = 0; kk < 14; kk += 2){
        bf16x8 aa[4];
        #pragma unroll
        for (int mt = 0; mt < 4; ++mt) aa[mt] = *(const bf16x8*)&ap[mt*16*AS];
        #pragma unroll
        for (int nt = 0; nt < 4; ++nt)
            #pragma unroll
            for (int mt = 0; mt < 4; ++mt)
                acc[mt][nt] = __builtin_amdgcn_mfma_f32_16x16x32_bf16(aa[mt], b0[nt], acc[mt][nt], 0, 0, 0);
        #pragma unroll
        for (int nt = 0; nt < 4; ++nt) b0[nt] = *(const bf16x8*)&wp[nt*512];
        #pragma unroll
        for (int mt = 0; mt < 4; ++mt) aa[mt] = *(const bf16x8*)&ap[mt*16*AS + 32];
        #pragma unroll
        for (int nt = 0; nt < 4; ++nt)
            #pragma unroll
            for (int mt = 0; mt < 4; ++mt)
                acc[mt][nt] = __builtin_amdgcn_mfma_f32_16x16x32_bf16(aa[mt], b1[nt], acc[mt][nt], 0, 0, 0);
        #pragma unroll
        for (int nt = 0; nt < 4; ++nt) b1[nt] = *(const bf16x8*)&wp[SLICE + nt*512];
        wp += 2*(size_t)SLICE; ap += 64;
    }
    {
        bf16x8 aa[4];
        #pragma unroll
        for (int mt = 0; mt < 4; ++mt) aa[mt] = *(const bf16x8*)&ap[mt*16*AS];
        #pragma unroll
        for (int nt = 0; nt < 4; ++nt)
            #pragma unroll
            for (int mt = 0; mt < 4; ++mt)
                acc[mt][nt] = __builtin_amdgcn_mfma_f32_16x16x32_bf16(aa[mt], b0[nt], acc[mt][nt], 0, 0, 0);
        #pragma unroll
        for (int mt = 0; mt < 4; ++mt) aa[mt] = *(const bf16x8*)&ap[mt*16*AS + 32];
        #pragma unroll
        for (int nt = 0; nt < 4; ++nt)
            #pragma unroll
            for (int mt = 0; mt < 4; ++mt)
                acc[mt][nt] = __builtin_amdgcn_mfma_f32_16x16x32_bf16(aa[mt], b1[nt], acc[mt][nt], 0, 0, 0);
    }
    __builtin_amdgcn_s_setprio(0);
}

// ======== phase helper functions (all inlined) ========
__device__ __forceinline__ void loadx(const float* __restrict__ xb, int w, int lane, float4 (&xs)[16]){
    #pragma unroll
    for (int rr = 0; rr < 8; ++rr){
        const float* xp = xb + (size_t)(w*8 + rr)*D + lane*8;
        xs[rr*2]   = *(const float4*)xp;
        xs[rr*2+1] = *(const float4*)(xp + 4);
    }
}

__device__ __forceinline__ void ln_store(const float4 (&xs)[16], bf16* At,
                                         const float* __restrict__ lg, const float* __restrict__ lb,
                                         int w, int lane){
    float4 lg0 = *(const float4*)&lg[lane*8], lg1 = *(const float4*)&lg[lane*8+4];
    float4 lb0 = *(const float4*)&lb[lane*8], lb1 = *(const float4*)&lb[lane*8+4];
    #pragma unroll
    for (int rr = 0; rr < 8; ++rr){
        float4 v0 = xs[rr*2], v1 = xs[rr*2+1];
        float s  = v0.x+v0.y+v0.z+v0.w + v1.x+v1.y+v1.z+v1.w;
        float sq = v0.x*v0.x+v0.y*v0.y+v0.z*v0.z+v0.w*v0.w
                 + v1.x*v1.x+v1.y*v1.y+v1.z*v1.z+v1.w*v1.w;
        #pragma unroll
        for (int o = 32; o; o >>= 1){ s += __shfl_xor(s,o); sq += __shfl_xor(sq,o); }
        float m = s*(1.f/D), var = sq*(1.f/D) - m*m, rstd = rsqrtf(var + 1e-5f);
        bf16x8 ov;
        ov[0] = (bf16)((v0.x-m)*rstd*lg0.x + lb0.x);
        ov[1] = (bf16)((v0.y-m)*rstd*lg0.y + lb0.y);
        ov[2] = (bf16)((v0.z-m)*rstd*lg0.z + lb0.z);
        ov[3] = (bf16)((v0.w-m)*rstd*lg0.w + lb0.w);
        ov[4] = (bf16)((v1.x-m)*rstd*lg1.x + lb1.x);
        ov[5] = (bf16)((v1.y-m)*rstd*lg1.y + lb1.y);
        ov[6] = (bf16)((v1.z-m)*rstd*lg1.z + lb1.z);
        ov[7] = (bf16)((v1.w-m)*rstd*lg1.w + lb1.w);
        *(bf16x8*)&At[(w*8 + rr)*AS + lane*8] = ov;
    }
}

__device__ __forceinline__ void softmax_head(f32x4 (&acc)[4][4], const float* __restrict__ bq,
                                             int wb, int l15){
    float bqv[4];
    #pragma unroll
    for (int nt = 0; nt < 4; ++nt) bqv[nt] = bq[wb + nt*16 + l15];
    #pragma unroll
    for (int mt = 0; mt < 4; ++mt)
        #pragma unroll
        for (int r = 0; r < 4; ++r){
            float v0 = acc[mt][0][r] + bqv[0];
            float v1 = acc[mt][1][r] + bqv[1];
            float v2 = acc[mt][2][r] + bqv[2];
            float v3 = acc[mt][3][r] + bqv[3];
            float mx = fmaxf(fmaxf(v0,v1), fmaxf(v2,v3));
            #pragma unroll
            for (int o = 1; o < 16; o <<= 1) mx = fmaxf(mx, __shfl_xor(mx, o));
            float e0 = __expf(v0-mx), e1 = __expf(v1-mx), e2 = __expf(v2-mx), e3 = __expf(v3-mx);
            float sden = e0+e1+e2+e3;
            #pragma unroll
            for (int o = 1; o < 16; o <<= 1) sden += __shfl_xor(sden, o);
            float inv = 1.f/sden;
            acc[mt][0][r] = e0*inv; acc[mt][1][r] = e1*inv;
            acc[mt][2][r] = e2*inv; acc[mt][3][r] = e3*inv;
        }
}

__device__ __forceinline__ void qstore_fence(const f32x4 (&acc)[4][4], bf16* At,
                                             int wb, int grp, int l15){
    #pragma unroll
    for (int mt = 0; mt < 4; ++mt)
        #pragma unroll
        for (int nt = 0; nt < 4; ++nt)
            #pragma unroll
            for (int r = 0; r < 4; ++r)
                At[(mt*16 + grp*4 + r)*AS + wb + nt*16 + l15] = (bf16)acc[mt][nt][r];
    asm volatile("s_waitcnt lgkmcnt(0)" ::: "memory");
    __builtin_amdgcn_sched_barrier(0);
}

__device__ __forceinline__ void phaseD(f32x4 (&acc)[4][4], const bf16* At,
                                       const bf16* __restrict__ attF, int b, int w,
                                       int wb, int l15, int grp, int lane){
    #pragma unroll
    for (int mt = 0; mt < 4; ++mt)
        #pragma unroll
        for (int nt = 0; nt < 4; ++nt) acc[mt][nt] = (f32x4){0.f,0.f,0.f,0.f};
    const bf16* ab = attF + (((size_t)b*H + w) << 12);
    bf16x8 bfr[2][4];
    #pragma unroll
    for (int ks = 0; ks < 2; ++ks)
        #pragma unroll
        for (int n4 = 0; n4 < 4; ++n4)
            bfr[ks][n4] = *(const bf16x8*)&ab[(n4*2 + ks)*512 + lane*8];
    #pragma unroll
    for (int ks = 0; ks < 2; ++ks){
        bf16x8 qa[4];
        #pragma unroll
        for (int mt = 0; mt < 4; ++mt)
            qa[mt] = *(const bf16x8*)&At[(mt*16 + l15)*AS + wb + ks*32 + grp*8];
        #pragma unroll
        for (int n4 = 0; n4 < 4; ++n4)
            #pragma unroll
            for (int mt = 0; mt < 4; ++mt)
                acc[mt][n4] = __builtin_amdgcn_mfma_f32_16x16x32_bf16(qa[mt], bfr[ks][n4], acc[mt][n4], 0, 0, 0);
    }
}

__device__ __forceinline__ void lnstats(const f32x4 (&acc)[4][4], float (*sts)[8], float (*stq)[8],
                                        int w, int grp, int l15){
    #pragma unroll
    for (int mt = 0; mt < 4; ++mt)
        #pragma unroll
        for (int r = 0; r < 4; ++r){
            float s = 0.f, q2 = 0.f;
            #pragma unroll
            for (int nt = 0; nt < 4; ++nt){ float v = acc[mt][nt][r]; s += v; q2 += v*v; }
            #pragma unroll
            for (int o = 1; o < 16; o <<= 1){ s += __shfl_xor(s, o); q2 += __shfl_xor(q2, o); }
            if (l15 == 0){ sts[mt*16 + grp*4 + r][w] = s; stq[mt*16 + grp*4 + r][w] = q2; }
        }
}

__device__ __forceinline__ void stylize(const f32x4 (&acc)[4][4], const float (*sts)[8],
                                        const float (*stq)[8], bf16* At,
                                        const float* __restrict__ sg, const float* __restrict__ sb,
                                        const float* __restrict__ ssb, int b,
                                        int wb, int grp, int l15){
    float sgv[4], sbv[4], sscv[4], sshv[4];
    #pragma unroll
    for (int nt = 0; nt < 4; ++nt){
        int col = wb + nt*16 + l15;
        sgv[nt] = sg[col]; sbv[nt] = sb[col];
        sscv[nt] = ssb[b*1024 + col]; sshv[nt] = ssb[b*1024 + 512 + col];
    }
    #pragma unroll
    for (int mt = 0; mt < 4; ++mt)
        #pragma unroll
        for (int r = 0; r < 4; ++r){
            int row = mt*16 + grp*4 + r;
            float4 s0 = *(const float4*)&sts[row][0];
            float4 s1 = *(const float4*)&sts[row][4];
            float4 q0 = *(const float4*)&stq[row][0];
            float4 q1 = *(const float4*)&stq[row][4];
            float m = (s0.x+s0.y+s0.z+s0.w + s1.x+s1.y+s1.z+s1.w)*(1.f/D);
            float var = (q0.x+q0.y+q0.z+q0.w + q1.x+q1.y+q1.z+q1.w)*(1.f/D) - m*m;
            float rstd = rsqrtf(var + 1e-5f);
            #pragma unroll
            for (int nt = 0; nt < 4; ++nt){
                float yn = (acc[mt][nt][r] - m)*rstd*sgv[nt] + sbv[nt];
                float h2 = yn*(1.f + sscv[nt]) + sshv[nt];
                At[row*AS + wb + nt*16 + l15] = (bf16)(h2 * sigmoidf_(h2));
            }
        }
}

__device__ __forceinline__ void ep_write(float* scr, const f32x4 (&acc)[4][4], int h,
                                         int wb, int grp, int l15){
    #pragma unroll
    for (int mt2 = 0; mt2 < 2; ++mt2){
        int mt = h*2 + mt2;
        #pragma unroll
        for (int nt = 0; nt < 4; ++nt)
            #pragma unroll
            for (int r = 0; r < 4; ++r)
                scr[(h*32 + mt2*16 + grp*4 + r)*516 + wb + nt*16 + l15] = acc[mt][nt][r];
    }
}

__device__ __forceinline__ void ep_rstore(const float* scr, const float* __restrict__ x,
                                          const float4 o4, float* __restrict__ out,
                                          long grow0, int h, int t){
    int colg = (t & 127) << 2, rb = t >> 7;
    #pragma unroll
    for (int i = 0; i < 8; ++i){
        int row = i*4 + rb;
        float4 v = *(const float4*)&scr[(h*32 + row)*516 + colg];
        size_t gi = (size_t)(grow0 + h*32 + row)*D + colg;
        float4 xb = *(const float4*)&x[gi];
        float4 r4 = {v.x+o4.x+xb.x, v.y+o4.y+xb.y, v.z+o4.z+xb.z, v.w+o4.w+xb.w};
        *(float4*)&out[gi] = r4;
    }
}

// ======== main fused kernel: 128 rows/block (2 pipelined tiles), 1 block/CU ========
__global__ __launch_bounds__(512) void k_main(
    const float* __restrict__ x, const bf16* __restrict__ WqS, const float* __restrict__ bq,
    const float* __restrict__ lg, const float* __restrict__ lb,
    const bf16* __restrict__ attF, const float* __restrict__ ssb,
    const float* __restrict__ sg, const float* __restrict__ sb,
    const bf16* __restrict__ oWS, const float* __restrict__ ob,
    float* __restrict__ out){
    __shared__ __align__(16) bf16 Abuf[2][MR*AS];   // 133 KB (also f32 scr 64x516 at EP)
    __shared__ float st_s[2][MR][8];
    __shared__ float st_q[2][MR][8];
    const int t = threadIdx.x, w = t >> 6, lane = t & 63;
    const int l15 = lane & 15, grp = lane >> 4;
    const long g0 = (long)blockIdx.x * 128;
    const int b = (int)(g0 / T);
    const int wb = w * 64;
    const size_t fragoff = (size_t)w*2048 + (size_t)l15*32 + (size_t)grp*8;
    float* scr = (float*)&Abuf[0][0];

    f32x4 acc0[4][4], acc1[4][4];
    float4 xs[16];

    // seg1: LN(tile0)
    loadx(x + (size_t)g0*D, w, lane, xs);
    ln_store(xs, Abuf[0], lg, lb, w, lane);
    __syncthreads();                                            // B1: Abuf0 ready

    // seg2: issue x-loads(tile1) -> GEMM1(tile0) -> LN(tile1)
    loadx(x + (size_t)(g0 + 64)*D, w, lane, xs);
    #pragma unroll
    for (int mt = 0; mt < 4; ++mt)
        #pragma unroll
        for (int nt = 0; nt < 4; ++nt) acc0[mt][nt] = (f32x4){0.f,0.f,0.f,0.f};
    gemm_body(WqS + fragoff, &Abuf[0][l15*AS + grp*8], acc0);
    ln_store(xs, Abuf[1], lg, lb, w, lane);
    __syncthreads();                                            // B2: Abuf1 ready, G1(0) reads done

    // seg3: SM/qst/D/LNst(tile0)  ||  GEMM1(tile1)
    softmax_head(acc0, bq, wb, l15);
    qstore_fence(acc0, Abuf[0], wb, grp, l15);
    phaseD(acc0, Abuf[0], attF, b, w, wb, l15, grp, lane);      // acc0 = y0
    #pragma unroll
    for (int mt = 0; mt < 4; ++mt)
        #pragma unroll
        for (int nt = 0; nt < 4; ++nt) acc1[mt][nt] = (f32x4){0.f,0.f,0.f,0.f};
    gemm_body(WqS + fragoff, &Abuf[1][l15*AS + grp*8], acc1);
    lnstats(acc0, st_s[0], st_q[0], w, grp, l15);
    __syncthreads();                                            // B3: st0 ready, G1(1) reads done

    // seg4: stylize(tile0)  ||  SM/qst/D/LNst(tile1)
    stylize(acc0, st_s[0], st_q[0], Abuf[0], sg, sb, ssb, b, wb, grp, l15);
    softmax_head(acc1, bq, wb, l15);
    qstore_fence(acc1, Abuf[1], wb, grp, l15);
    phaseD(acc1, Abuf[1], attF, b, w, wb, l15, grp, lane);      // acc1 = y1
    lnstats(acc1, st_s[1], st_q[1], w, grp, l15);
    __syncthreads();                                            // B4: h0 ready, st1 ready

    // seg5: GEMM2(tile0)  ||  stylize(tile1)
    #pragma unroll
    for (int mt = 0; mt < 4; ++mt)
        #pragma unroll
        for (int nt = 0; nt < 4; ++nt) acc0[mt][nt] = (f32x4){0.f,0.f,0.f,0.f};
    gemm_body(oWS + fragoff, &Abuf[0][l15*AS + grp*8], acc0);
    stylize(acc1, st_s[1], st_q[1], Abuf[1], sg, sb, ssb, b, wb, grp, l15);
    __syncthreads();                                            // B5: G2(0) reads done, h1 ready

    // seg6: GEMM2(tile1)  ||  ep-write(t0,h0) (scr rows 0-31 live in Abuf0 only)
    #pragma unroll
    for (int mt = 0; mt < 4; ++mt)
        #pragma unroll
        for (int nt = 0; nt < 4; ++nt) acc1[mt][nt] = (f32x4){0.f,0.f,0.f,0.f};
    gemm_body(oWS + fragoff, &Abuf[1][l15*AS + grp*8], acc1);
    ep_write(scr, acc0, 0, wb, grp, l15);
    __syncthreads();                                            // B6

    // pipelined epilogue: rstore reads one 32-row half while ep_write fills the other
    float4 o4 = *(const float4*)&ob[(t & 127) << 2];
    ep_rstore(scr, x, o4, out, g0, 0, t);
    ep_write(scr, acc0, 1, wb, grp, l15);
    __syncthreads();                                            // B7
    ep_rstore(scr, x, o4, out, g0, 1, t);                       // tile0 rows 32..63
    ep_write(scr, acc1, 0, wb, grp, l15);
    __syncthreads();                                            // B8
    ep_rstore(scr, x, o4, out, g0 + 64, 0, t);
    ep_write(scr, acc1, 1, wb, grp, l15);
    __syncthreads();                                            // B9
    ep_rstore(scr, x, o4, out, g0 + 64, 1, t);
}

extern "C" void kernel_launch(void* const* d_in, const int* in_sizes, int n_in,
                              void* d_out, int out_size, void* d_ws, size_t ws_size,
                              hipStream_t stream){
    const float* x     = (const float*)d_in[0];
    const float* xf    = (const float*)d_in[1];
    const float* emb   = (const float*)d_in[2];
    const float* Wq    = (const float*)d_in[3];
    const float* bq    = (const float*)d_in[4];
    const float* Wk    = (const float*)d_in[5];
    const float* bk    = (const float*)d_in[6];
    const float* Wv    = (const float*)d_in[7];
    const float* bv    = (const float*)d_in[8];
    const float* ln_g  = (const float*)d_in[9];
    const float* ln_b  = (const float*)d_in[10];
    const float* tln_g = (const float*)d_in[11];
    const float* tln_b = (const float*)d_in[12];
    const float* emb_W = (const float*)d_in[13];
    const float* emb_b = (const float*)d_in[14];
    const float* sn_g  = (const float*)d_in[15];
    const float* sn_b  = (const float*)d_in[16];
    const float* out_W = (const float*)d_in[17];
    const float* out_b = (const float*)d_in[18];
    float* out = (float*)d_out;

    // workspace carve
    float* ssb  = (float*)d_ws;                          // B*1024 f32
    bf16*  kbuf = (bf16*)(ssb + B*1024);                 // B*NN*D bf16
    bf16*  vbuf = kbuf + (size_t)B*NN*D;                 // B*NN*D bf16
    bf16*  attF = vbuf + (size_t)B*NN*D;                 // B*H*DH*DH bf16
    bf16*  wqS  = attF + (size_t)B*H*DH*DH;              // D*D bf16 (staged layout)
    bf16*  owS  = wqS  + (size_t)D*D;                    // D*D bf16

    k_prep<<<dim3(512),     dim3(256), 0, stream>>>(xf, Wk, bk, Wv, bv, tln_g, tln_b, kbuf, vbuf);
    k_att2<<<dim3(224),     dim3(256), 0, stream>>>(kbuf, vbuf, attF, Wq, out_W, wqS, owS,
                                                    emb, emb_W, emb_b, ssb);
    k_main<<<dim3(B*T/128), dim3(512), 0, stream>>>(x, wqS, bq, ln_g, ln_b, attF, ssb,
                                                    sn_g, sn_b, owS, out_b, out);
}

// Round 14
// 161.578 us; speedup vs baseline: 1.2063x; 1.2063x over previous
//
#include <hip/hip_runtime.h>
#include <math.h>
#include <stdint.h>

#define B 4
#define T 8192
#define D 512
#define NN 256
#define L 768
#define TE 2048
#define H 8
#define DH 64
#define MR 64
#define AS 520          // Abuf row stride (bf16 elems)
#define SLICE 16384     // elems per 32-K staged B slice (512 cols * 32 k)

typedef __bf16 bf16;
typedef bf16  bf16x8 __attribute__((ext_vector_type(8)));
typedef float f32x4  __attribute__((ext_vector_type(4)));

__device__ __forceinline__ float sigmoidf_(float x){ return 1.0f/(1.0f+__expf(-x)); }

// ======== k_prep: kv only — LN(xf) + k/v projection (8 rows x 128-col quarter) ========
__global__ __launch_bounds__(256) void k_prep(
    const float* __restrict__ xf, const float* __restrict__ Wk,
    const float* __restrict__ bk, const float* __restrict__ Wv,
    const float* __restrict__ bv, const float* __restrict__ tg,
    const float* __restrict__ tb, bf16* __restrict__ kbuf, bf16* __restrict__ vbuf){
    __shared__ float xfn[8][L];
    const int bid = blockIdx.x, t = threadIdx.x;
    int g0 = (bid >> 2) * 8, jc = bid & 3;
    int wave = t >> 6, lane = t & 63;
    #pragma unroll
    for (int rr = 0; rr < 2; ++rr){
        int r = wave*2 + rr, g = g0 + r;
        float vals[12];
        float s = 0.f, sq = 0.f;
        #pragma unroll
        for (int i = 0; i < 12; ++i){ float v = xf[(size_t)g*L + lane*12 + i]; vals[i] = v; s += v; sq += v*v; }
        #pragma unroll
        for (int o = 32; o; o >>= 1){ s += __shfl_xor(s, o); sq += __shfl_xor(sq, o); }
        float m = s / L; float var = sq / L - m*m;
        float rstd = rsqrtf(var + 1e-5f);
        #pragma unroll
        for (int i = 0; i < 12; ++i){
            int l = lane*12 + i;
            xfn[r][l] = (vals[i]-m)*rstd*tg[l] + tb[l];
        }
    }
    __syncthreads();
    const float* Wm = (t < 128) ? Wk : Wv;
    int col = jc*128 + (t & 127);
    float acc[8];
    #pragma unroll
    for (int r = 0; r < 8; ++r) acc[r] = 0.f;
    for (int l = 0; l < L; l += 4){
        float4 xv[8];
        #pragma unroll
        for (int r = 0; r < 8; ++r) xv[r] = *(const float4*)&xfn[r][l];
        #pragma unroll
        for (int u = 0; u < 4; ++u){
            float wv = Wm[(size_t)(l+u)*D + col];
            #pragma unroll
            for (int r = 0; r < 8; ++r) acc[r] += ((const float*)&xv[r])[u] * wv;
        }
    }
    float bias = (t < 128) ? bk[col] : bv[col];
    bf16* dst = (t < 128) ? kbuf : vbuf;
    #pragma unroll
    for (int r = 0; r < 8; ++r){
        size_t g = (size_t)(g0 + r);
        dst[g*D + col] = (bf16)(acc[r] + bias);
    }
}

// ======== k_att2: attn state + weight re-layout + ss ========
__global__ __launch_bounds__(256) void k_att2(
    const bf16* __restrict__ kbuf, const bf16* __restrict__ vbuf, bf16* __restrict__ attF,
    const float* __restrict__ Wq, const float* __restrict__ oW,
    bf16* __restrict__ wqS, bf16* __restrict__ owS,
    const float* __restrict__ emb, const float* __restrict__ emb_W,
    const float* __restrict__ emb_b, float* __restrict__ ss){
    __shared__ __align__(16) char smem[133120];
    const int bid = blockIdx.x, t = threadIdx.x;
    if (bid < 32){
        float* kh = (float*)smem;
        float* vh = kh + NN*DH;
        float (*pm)[DH] = (float(*)[DH])(vh + NN*DH);
        float (*ps)[DH] = pm + 4;
        int h = bid & 7, b = bid >> 3;
        for (int k = 0; k < NN*DH/256; ++k){
            int m = k*256 + t;
            int n = m >> 6, dl = m & 63;
            size_t src = (size_t)(b*NN + n)*D + h*DH + dl;
            kh[m] = (float)kbuf[src]; vh[m] = (float)vbuf[src];
        }
        __syncthreads();
        int d = t & 63, c = t >> 6;
        float mx = -1e30f;
        for (int n = c*64; n < c*64+64; ++n) mx = fmaxf(mx, kh[n*DH + d]);
        pm[c][d] = mx;
        __syncthreads();
        mx = fmaxf(fmaxf(pm[0][d], pm[1][d]), fmaxf(pm[2][d], pm[3][d]));
        float s = 0.f;
        for (int n = c*64; n < c*64+64; ++n){ float e = __expf(kh[n*DH + d] - mx); kh[n*DH + d] = e; s += e; }
        ps[c][d] = s;
        __syncthreads();
        float inv = 1.f/(ps[0][d] + ps[1][d] + ps[2][d] + ps[3][d]);
        for (int n = c*64; n < c*64+64; ++n) kh[n*DH + d] *= inv;
        __syncthreads();
        int l = t >> 2, dd0 = (t & 3)*16;
        float acc[16];
        #pragma unroll
        for (int i = 0; i < 16; ++i) acc[i] = 0.f;
        for (int n = 0; n < NN; ++n){
            float vv = vh[n*DH + l];
            #pragma unroll
            for (int i = 0; i < 16; ++i) acc[i] += kh[n*DH + dd0 + i] * vv;
        }
        size_t hbase = ((size_t)(b*H + h)) << 12;
        #pragma unroll
        for (int half = 0; half < 2; ++half){
            int d0 = dd0 + half*8;
            int f  = (l >> 4)*2 + (d0 >> 5);
            int ln = ((d0 >> 3) & 3)*16 + (l & 15);
            bf16x8 ov;
            #pragma unroll
            for (int j = 0; j < 8; ++j) ov[j] = (bf16)acc[half*8 + j];
            *(bf16x8*)&attF[hbase + f*512 + ln*8] = ov;
        }
    } else if (bid < 160){
        int lb2 = bid - 32;
        const float* W = (lb2 < 64) ? Wq : oW;
        bf16* Wst = (lb2 < 64) ? wqS : owS;
        int lb = lb2 & 63;
        int k0 = (lb & 7)*64, n0 = (lb >> 3)*64;
        float (*tile)[65] = (float(*)[65])smem;
        int c = t & 63, r4 = t >> 6;
        #pragma unroll
        for (int p = 0; p < 16; ++p){ int r = p*4 + r4; tile[r][c] = W[(size_t)(k0+r)*D + n0 + c]; }
        __syncthreads();
        int oct = t >> 6, col = t & 63;
        #pragma unroll
        for (int half = 0; half < 2; ++half){
            int kk = (lb & 7)*2 + half;
            bf16x8 ov;
            #pragma unroll
            for (int j = 0; j < 8; ++j) ov[j] = (bf16)tile[half*32 + oct*8 + j][col];
            *(bf16x8*)&Wst[(size_t)kk*SLICE + (n0+col)*32 + oct*8] = ov;
        }
    } else {
        float (*semb)[TE] = (float(*)[TE])smem;
        float (*red)[64]  = (float(*)[64])(smem + 4*TE*4);
        int c = bid - 160;
        for (int i = t; i < TE; i += 256)
            #pragma unroll
            for (int b = 0; b < B; ++b){ float e = emb[b*TE + i]; semb[b][i] = e * sigmoidf_(e); }
        __syncthreads();
        int o = t & 15, p = t >> 4;
        int j = c*16 + o;
        float acc[B] = {0.f,0.f,0.f,0.f};
        for (int i = 0; i < 128; ++i){
            int e = p*128 + i;
            float wv = emb_W[(size_t)e*1024 + j];
            #pragma unroll
            for (int b = 0; b < B; ++b) acc[b] += semb[b][e] * wv;
        }
        #pragma unroll
        for (int b = 0; b < B; ++b) red[p][b*16 + o] = acc[b];
        __syncthreads();
        if (t < 64){
            int b = t >> 4, o2 = t & 15;
            int j2 = c*16 + o2;
            float s = 0.f;
            #pragma unroll
            for (int pp = 0; pp < 16; ++pp) s += red[pp][b*16 + o2];
            ss[b*1024 + j2] = s + emb_b[j2];
        }
    }
}

// ======== preload first 2 slices (issued EARLY, latency hides under preceding VALU phase) ========
__device__ __forceinline__ void preload2(const bf16* __restrict__ wfrag,
                                         bf16x8 (&b0)[4], bf16x8 (&b1)[4]){
    #pragma unroll
    for (int nt = 0; nt < 4; ++nt) b0[nt] = *(const bf16x8*)&wfrag[nt*512];
    #pragma unroll
    for (int nt = 0; nt < 4; ++nt) b1[nt] = *(const bf16x8*)&wfrag[SLICE + nt*512];
}

// ======== rolled GEMM over K=512, first 2 slices preloaded (+T5 setprio) ========
__device__ __forceinline__ void gemm_rest(const bf16* __restrict__ wfrag,
                                          const bf16* __restrict__ afrag,
                                          bf16x8 (&b0)[4], bf16x8 (&b1)[4],
                                          f32x4 (&acc)[4][4]){
    const bf16* wp = wfrag + 2*(size_t)SLICE;
    const bf16* ap = afrag;
    __builtin_amdgcn_s_setprio(1);
    for (int kk = 0; kk < 14; kk += 2){
        bf16x8 aa[4];
        #pragma unroll
        for (int mt = 0; mt < 4; ++mt) aa[mt] = *(const bf16x8*)&ap[mt*16*AS];
        #pragma unroll
        for (int nt = 0; nt < 4; ++nt)
            #pragma unroll
            for (int mt = 0; mt < 4; ++mt)
                acc[mt][nt] = __builtin_amdgcn_mfma_f32_16x16x32_bf16(aa[mt], b0[nt], acc[mt][nt], 0, 0, 0);
        #pragma unroll
        for (int nt = 0; nt < 4; ++nt) b0[nt] = *(const bf16x8*)&wp[nt*512];
        #pragma unroll
        for (int mt = 0; mt < 4; ++mt) aa[mt] = *(const bf16x8*)&ap[mt*16*AS + 32];
        #pragma unroll
        for (int nt = 0; nt < 4; ++nt)
            #pragma unroll
            for (int mt = 0; mt < 4; ++mt)
                acc[mt][nt] = __builtin_amdgcn_mfma_f32_16x16x32_bf16(aa[mt], b1[nt], acc[mt][nt], 0, 0, 0);
        #pragma unroll
        for (int nt = 0; nt < 4; ++nt) b1[nt] = *(const bf16x8*)&wp[SLICE + nt*512];
        wp += 2*(size_t)SLICE; ap += 64;
    }
    {
        bf16x8 aa[4];
        #pragma unroll
        for (int mt = 0; mt < 4; ++mt) aa[mt] = *(const bf16x8*)&ap[mt*16*AS];
        #pragma unroll
        for (int nt = 0; nt < 4; ++nt)
            #pragma unroll
            for (int mt = 0; mt < 4; ++mt)
                acc[mt][nt] = __builtin_amdgcn_mfma_f32_16x16x32_bf16(aa[mt], b0[nt], acc[mt][nt], 0, 0, 0);
        #pragma unroll
        for (int mt = 0; mt < 4; ++mt) aa[mt] = *(const bf16x8*)&ap[mt*16*AS + 32];
        #pragma unroll
        for (int nt = 0; nt < 4; ++nt)
            #pragma unroll
            for (int mt = 0; mt < 4; ++mt)
                acc[mt][nt] = __builtin_amdgcn_mfma_f32_16x16x32_bf16(aa[mt], b1[nt], acc[mt][nt], 0, 0, 0);
    }
    __builtin_amdgcn_s_setprio(0);
}

// ======== main fused kernel: 64 rows/block, 8 waves (1 head each), 2 blocks/CU ========
__global__ __launch_bounds__(512, 4) void k_main(
    const float* __restrict__ x, const bf16* __restrict__ WqS, const float* __restrict__ bq,
    const float* __restrict__ lg, const float* __restrict__ lb,
    const bf16* __restrict__ attF, const float* __restrict__ ssb,
    const float* __restrict__ sg, const float* __restrict__ sb,
    const bf16* __restrict__ oWS, const float* __restrict__ ob,
    float* __restrict__ out){
    __shared__ __align__(16) bf16 Abuf[MR*AS];      // 66.6 KB: LN(x) -> q -> silu(h) -> f32 scratch
    __shared__ float st_s[MR][8];
    __shared__ float st_q[MR][8];
    const int t = threadIdx.x, w = t >> 6, lane = t & 63;
    const int l15 = lane & 15, grp = lane >> 4;
    const long g0 = (long)blockIdx.x * MR;
    const int b = (int)(g0 / T);
    const int wb = w * 64;
    const size_t fragoff = (size_t)w*2048 + (size_t)l15*32 + (size_t)grp*8;

    // ---- T14 hoist: issue GEMM1 slices 0,1 NOW; latency hides under the LN phase.
    bf16x8 b0[4], b1[4];
    preload2(WqS + fragoff, b0, b1);

    // ---- phase A: LN(x) -> Abuf bf16 (8 rows per wave, rolled)
    {
        float4 lg0 = *(const float4*)&lg[lane*8], lg1 = *(const float4*)&lg[lane*8+4];
        float4 lb0 = *(const float4*)&lb[lane*8], lb1 = *(const float4*)&lb[lane*8+4];
        #pragma unroll 2
        for (int rr = 0; rr < 8; ++rr){
            int r = w*8 + rr;
            const float* xp = &x[(size_t)(g0 + r)*D + lane*8];
            float4 v0 = *(const float4*)xp, v1 = *(const float4*)(xp+4);
            float s  = v0.x+v0.y+v0.z+v0.w + v1.x+v1.y+v1.z+v1.w;
            float sq = v0.x*v0.x+v0.y*v0.y+v0.z*v0.z+v0.w*v0.w
                     + v1.x*v1.x+v1.y*v1.y+v1.z*v1.z+v1.w*v1.w;
            #pragma unroll
            for (int o = 32; o; o >>= 1){ s += __shfl_xor(s,o); sq += __shfl_xor(sq,o); }
            float m = s*(1.f/D), var = sq*(1.f/D) - m*m, rstd = rsqrtf(var + 1e-5f);
            bf16x8 ov;
            ov[0] = (bf16)((v0.x-m)*rstd*lg0.x + lb0.x);
            ov[1] = (bf16)((v0.y-m)*rstd*lg0.y + lb0.y);
            ov[2] = (bf16)((v0.z-m)*rstd*lg0.z + lb0.z);
            ov[3] = (bf16)((v0.w-m)*rstd*lg0.w + lb0.w);
            ov[4] = (bf16)((v1.x-m)*rstd*lg1.x + lb1.x);
            ov[5] = (bf16)((v1.y-m)*rstd*lg1.y + lb1.y);
            ov[6] = (bf16)((v1.z-m)*rstd*lg1.z + lb1.z);
            ov[7] = (bf16)((v1.w-m)*rstd*lg1.w + lb1.w);
            *(bf16x8*)&Abuf[r*AS + lane*8] = ov;
        }
    }
    __syncthreads();

    // ---- GEMM1: q = LN(x) @ Wq  (slices 0,1 already resident)
    f32x4 acc[4][4];
    #pragma unroll
    for (int mt = 0; mt < 4; ++mt)
        #pragma unroll
        for (int nt = 0; nt < 4; ++nt) acc[mt][nt] = (f32x4){0.f,0.f,0.f,0.f};
    gemm_rest(WqS + fragoff, &Abuf[l15*AS + grp*8], b0, b1, acc);

    // ---- attF prefetch (L2) — lands during softmax, consumed in phase D
    bf16x8 bfr[2][4];
    {
        const bf16* ab = attF + (((size_t)b*H + w) << 12);
        #pragma unroll
        for (int ks = 0; ks < 2; ++ks)
            #pragma unroll
            for (int n4 = 0; n4 < 4; ++n4)
                bfr[ks][n4] = *(const bf16x8*)&ab[(n4*2 + ks)*512 + lane*8];
    }

    // ---- softmax over this wave's head (in-register)
    {
        float bqv[4];
        #pragma unroll
        for (int nt = 0; nt < 4; ++nt) bqv[nt] = bq[wb + nt*16 + l15];
        #pragma unroll
        for (int mt = 0; mt < 4; ++mt)
            #pragma unroll
            for (int r = 0; r < 4; ++r){
                float v0 = acc[mt][0][r] + bqv[0];
                float v1 = acc[mt][1][r] + bqv[1];
                float v2 = acc[mt][2][r] + bqv[2];
                float v3 = acc[mt][3][r] + bqv[3];
                float mx = fmaxf(fmaxf(v0,v1), fmaxf(v2,v3));
                #pragma unroll
                for (int o = 1; o < 16; o <<= 1) mx = fmaxf(mx, __shfl_xor(mx, o));
                float e0 = __expf(v0-mx), e1 = __expf(v1-mx), e2 = __expf(v2-mx), e3 = __expf(v3-mx);
                float sden = e0+e1+e2+e3;
                #pragma unroll
                for (int o = 1; o < 16; o <<= 1) sden += __shfl_xor(sden, o);
                float inv = 1.f/sden;
                acc[mt][0][r] = e0*inv; acc[mt][1][r] = e1*inv;
                acc[mt][2][r] = e2*inv; acc[mt][3][r] = e3*inv;
            }
    }
    __syncthreads();   // all waves done reading Abuf (A of GEMM1) before overwrite

    // q (bf16) -> Abuf [all 64 rows][own 64 cols] — wave-local region
    #pragma unroll
    for (int mt = 0; mt < 4; ++mt)
        #pragma unroll
        for (int nt = 0; nt < 4; ++nt)
            #pragma unroll
            for (int r = 0; r < 4; ++r)
                Abuf[(mt*16 + grp*4 + r)*AS + wb + nt*16 + l15] = (bf16)acc[mt][nt][r];
    // wave-local write->read: LDS wait + scheduling fence (rule #18), no block barrier
    asm volatile("s_waitcnt lgkmcnt(0)" ::: "memory");
    __builtin_amdgcn_sched_barrier(0);

    // ---- phase D: y = q @ att[head w]  (B already in registers)
    #pragma unroll
    for (int mt = 0; mt < 4; ++mt)
        #pragma unroll
        for (int nt = 0; nt < 4; ++nt) acc[mt][nt] = (f32x4){0.f,0.f,0.f,0.f};
    #pragma unroll
    for (int ks = 0; ks < 2; ++ks){
        bf16x8 qa[4];
        #pragma unroll
        for (int mt = 0; mt < 4; ++mt)
            qa[mt] = *(const bf16x8*)&Abuf[(mt*16 + l15)*AS + wb + ks*32 + grp*8];
        #pragma unroll
        for (int n4 = 0; n4 < 4; ++n4)
            #pragma unroll
            for (int mt = 0; mt < 4; ++mt)
                acc[mt][n4] = __builtin_amdgcn_mfma_f32_16x16x32_bf16(qa[mt], bfr[ks][n4], acc[mt][n4], 0, 0, 0);
    }

    // ---- LN(y) stats: per-wave partials -> LDS -> combine
    #pragma unroll
    for (int mt = 0; mt < 4; ++mt)
        #pragma unroll
        for (int r = 0; r < 4; ++r){
            float s = 0.f, q2 = 0.f;
            #pragma unroll
            for (int nt = 0; nt < 4; ++nt){ float v = acc[mt][nt][r]; s += v; q2 += v*v; }
            #pragma unroll
            for (int o = 1; o < 16; o <<= 1){ s += __shfl_xor(s, o); q2 += __shfl_xor(q2, o); }
            if (l15 == 0){ st_s[mt*16 + grp*4 + r][w] = s; st_q[mt*16 + grp*4 + r][w] = q2; }
        }
    __syncthreads();

    // ---- T14 hoist: issue GEMM2 slices 0,1 NOW; latency hides under stylize.
    preload2(oWS + fragoff, b0, b1);

    // ---- stylize + silu -> Abuf bf16
    {
        float sgv[4], sbv[4], sscv[4], sshv[4];
        #pragma unroll
        for (int nt = 0; nt < 4; ++nt){
            int col = wb + nt*16 + l15;
            sgv[nt] = sg[col]; sbv[nt] = sb[col];
            sscv[nt] = ssb[b*1024 + col]; sshv[nt] = ssb[b*1024 + 512 + col];
        }
        #pragma unroll
        for (int mt = 0; mt < 4; ++mt)
            #pragma unroll
            for (int r = 0; r < 4; ++r){
                int row = mt*16 + grp*4 + r;
                float4 s0 = *(const float4*)&st_s[row][0];
                float4 s1 = *(const float4*)&st_s[row][4];
                float4 q0 = *(const float4*)&st_q[row][0];
                float4 q1 = *(const float4*)&st_q[row][4];
                float m = (s0.x+s0.y+s0.z+s0.w + s1.x+s1.y+s1.z+s1.w)*(1.f/D);
                float var = (q0.x+q0.y+q0.z+q0.w + q1.x+q1.y+q1.z+q1.w)*(1.f/D) - m*m;
                float rstd = rsqrtf(var + 1e-5f);
                #pragma unroll
                for (int nt = 0; nt < 4; ++nt){
                    float yn = (acc[mt][nt][r] - m)*rstd*sgv[nt] + sbv[nt];
                    float h2 = yn*(1.f + sscv[nt]) + sshv[nt];
                    Abuf[row*AS + wb + nt*16 + l15] = (bf16)(h2 * sigmoidf_(h2));
                }
            }
    }
    __syncthreads();   // h complete across all waves before GEMM2 reads full K

    // ---- GEMM2: out_pre = silu(h) @ out_W  (slices 0,1 already resident)
    #pragma unroll
    for (int mt = 0; mt < 4; ++mt)
        #pragma unroll
        for (int nt = 0; nt < 4; ++nt) acc[mt][nt] = (f32x4){0.f,0.f,0.f,0.f};
    gemm_rest(oWS + fragoff, &Abuf[l15*AS + grp*8], b0, b1, acc);

    // ---- epilogue: LDS-bounce transpose -> coalesced (acc + ob + x) stores
    float* scr = (float*)Abuf;              // 32 rows x stride 516 f32 (66048B <= 66560B)
    #pragma unroll
    for (int half = 0; half < 2; ++half){
        __syncthreads();    // half0: all GEMM2 LDS reads done; half1: prev flush reads done
        #pragma unroll
        for (int mt2 = 0; mt2 < 2; ++mt2){
            int mt = half*2 + mt2;
            #pragma unroll
            for (int nt = 0; nt < 4; ++nt)
                #pragma unroll
                for (int r = 0; r < 4; ++r)
                    scr[(mt2*16 + grp*4 + r)*516 + wb + nt*16 + l15] = acc[mt][nt][r];
        }
        __syncthreads();
        #pragma unroll 2
        for (int i = 0; i < 8; ++i){
            int c = i*512 + t;
            int row = c >> 7, col4 = (c & 127) << 2;
            float4 v  = *(const float4*)&scr[row*516 + col4];
            size_t gi = (size_t)(g0 + half*32 + row)*D + col4;
            float4 xb = *(const float4*)&x[gi];
            float4 o4 = *(const float4*)&ob[col4];
            float4 r4 = {v.x+o4.x+xb.x, v.y+o4.y+xb.y, v.z+o4.z+xb.z, v.w+o4.w+xb.w};
            *(float4*)&out[gi] = r4;
        }
    }
}

extern "C" void kernel_launch(void* const* d_in, const int* in_sizes, int n_in,
                              void* d_out, int out_size, void* d_ws, size_t ws_size,
                              hipStream_t stream){
    const float* x     = (const float*)d_in[0];
    const float* xf    = (const float*)d_in[1];
    const float* emb   = (const float*)d_in[2];
    const float* Wq    = (const float*)d_in[3];
    const float* bq    = (const float*)d_in[4];
    const float* Wk    = (const float*)d_in[5];
    const float* bk    = (const float*)d_in[6];
    const float* Wv    = (const float*)d_in[7];
    const float* bv    = (const float*)d_in[8];
    const float* ln_g  = (const float*)d_in[9];
    const float* ln_b  = (const float*)d_in[10];
    const float* tln_g = (const float*)d_in[11];
    const float* tln_b = (const float*)d_in[12];
    const float* emb_W = (const float*)d_in[13];
    const float* emb_b = (const float*)d_in[14];
    const float* sn_g  = (const float*)d_in[15];
    const float* sn_b  = (const float*)d_in[16];
    const float* out_W = (const float*)d_in[17];
    const float* out_b = (const float*)d_in[18];
    float* out = (float*)d_out;

    // workspace carve
    float* ssb  = (float*)d_ws;                          // B*1024 f32
    bf16*  kbuf = (bf16*)(ssb + B*1024);                 // B*NN*D bf16
    bf16*  vbuf = kbuf + (size_t)B*NN*D;                 // B*NN*D bf16
    bf16*  attF = vbuf + (size_t)B*NN*D;                 // B*H*DH*DH bf16
    bf16*  wqS  = attF + (size_t)B*H*DH*DH;              // D*D bf16 (staged layout)
    bf16*  owS  = wqS  + (size_t)D*D;                    // D*D bf16

    k_prep<<<dim3(512),    dim3(256), 0, stream>>>(xf, Wk, bk, Wv, bv, tln_g, tln_b, kbuf, vbuf);
    k_att2<<<dim3(224),    dim3(256), 0, stream>>>(kbuf, vbuf, attF, Wq, out_W, wqS, owS,
                                                   emb, emb_W, emb_b, ssb);
    k_main<<<dim3(B*T/MR), dim3(512), 0, stream>>>(x, wqS, bq, ln_g, ln_b, attF, ssb,
                                                   sn_g, sn_b, owS, out_b, out);
}

// Round 15
// 153.496 us; speedup vs baseline: 1.2698x; 1.0527x over previous
//
#include <hip/hip_runtime.h>
#include <math.h>
#include <stdint.h>

#define B 4
#define T 8192
#define D 512
#define NN 256
#define L 768
#define TE 2048
#define H 8
#define DH 64
#define MR 64
#define AS 520          // Abuf row stride (bf16 elems)
#define SLICE 16384     // elems per 32-K staged B slice (512 cols * 32 k)

typedef __bf16 bf16;
typedef bf16  bf16x8 __attribute__((ext_vector_type(8)));
typedef float f32x4  __attribute__((ext_vector_type(4)));

__device__ __forceinline__ float sigmoidf_(float x){ return 1.0f/(1.0f+__expf(-x)); }

// ======== k_prep_all: ALL independent prep work in one launch ========
// [0,512): kv — LN(xf) + k/v projection (8 rows x 128-col quarter)
// [512,640): weight re-layout W (f32 [k][n]) -> Wst bf16 [kk][col][k']
// [640,704): ss = silu(emb) @ emb_W + emb_b (all 4 batches; block owns 16 cols)
__global__ __launch_bounds__(256) void k_prep_all(
    const float* __restrict__ xf, const float* __restrict__ Wk,
    const float* __restrict__ bk, const float* __restrict__ Wv,
    const float* __restrict__ bv, const float* __restrict__ tg,
    const float* __restrict__ tb, bf16* __restrict__ kbuf, bf16* __restrict__ vbuf,
    const float* __restrict__ Wq, const float* __restrict__ oW,
    bf16* __restrict__ wqS, bf16* __restrict__ owS,
    const float* __restrict__ emb, const float* __restrict__ emb_W,
    const float* __restrict__ emb_b, float* __restrict__ ss){
    __shared__ __align__(16) char smem[40960];
    const int bid = blockIdx.x, t = threadIdx.x;
    if (bid < 512){
        // ---- kv projection
        float (*xfn)[L] = (float(*)[L])smem;                    // 24 KB
        int g0 = (bid >> 2) * 8, jc = bid & 3;
        int wave = t >> 6, lane = t & 63;
        #pragma unroll
        for (int rr = 0; rr < 2; ++rr){
            int r = wave*2 + rr, g = g0 + r;
            float vals[12];
            float s = 0.f, sq = 0.f;
            #pragma unroll
            for (int i = 0; i < 12; ++i){ float v = xf[(size_t)g*L + lane*12 + i]; vals[i] = v; s += v; sq += v*v; }
            #pragma unroll
            for (int o = 32; o; o >>= 1){ s += __shfl_xor(s, o); sq += __shfl_xor(sq, o); }
            float m = s / L; float var = sq / L - m*m;
            float rstd = rsqrtf(var + 1e-5f);
            #pragma unroll
            for (int i = 0; i < 12; ++i){
                int l = lane*12 + i;
                xfn[r][l] = (vals[i]-m)*rstd*tg[l] + tb[l];
            }
        }
        __syncthreads();
        const float* Wm = (t < 128) ? Wk : Wv;
        int col = jc*128 + (t & 127);
        float acc[8];
        #pragma unroll
        for (int r = 0; r < 8; ++r) acc[r] = 0.f;
        for (int l = 0; l < L; l += 4){
            float4 xv[8];
            #pragma unroll
            for (int r = 0; r < 8; ++r) xv[r] = *(const float4*)&xfn[r][l];
            #pragma unroll
            for (int u = 0; u < 4; ++u){
                float wv = Wm[(size_t)(l+u)*D + col];
                #pragma unroll
                for (int r = 0; r < 8; ++r) acc[r] += ((const float*)&xv[r])[u] * wv;
            }
        }
        float bias = (t < 128) ? bk[col] : bv[col];
        bf16* dst = (t < 128) ? kbuf : vbuf;
        #pragma unroll
        for (int r = 0; r < 8; ++r){
            size_t g = (size_t)(g0 + r);
            dst[g*D + col] = (bf16)(acc[r] + bias);
        }
    } else if (bid < 640){
        // ---- weight re-layout
        int lb2 = bid - 512;
        const float* W = (lb2 < 64) ? Wq : oW;
        bf16* Wst = (lb2 < 64) ? wqS : owS;
        int lb = lb2 & 63;
        int k0 = (lb & 7)*64, n0 = (lb >> 3)*64;
        float (*tile)[65] = (float(*)[65])smem;                 // 16.6 KB
        int c = t & 63, r4 = t >> 6;
        #pragma unroll
        for (int p = 0; p < 16; ++p){ int r = p*4 + r4; tile[r][c] = W[(size_t)(k0+r)*D + n0 + c]; }
        __syncthreads();
        int oct = t >> 6, col = t & 63;
        #pragma unroll
        for (int half = 0; half < 2; ++half){
            int kk = (lb & 7)*2 + half;
            bf16x8 ov;
            #pragma unroll
            for (int j = 0; j < 8; ++j) ov[j] = (bf16)tile[half*32 + oct*8 + j][col];
            *(bf16x8*)&Wst[(size_t)kk*SLICE + (n0+col)*32 + oct*8] = ov;
        }
    } else {
        // ---- ss
        float (*semb)[TE] = (float(*)[TE])smem;                 // 32 KB
        float (*red)[64]  = (float(*)[64])(smem + 4*TE*4);      // 4 KB
        int c = bid - 640;
        for (int i = t; i < TE; i += 256)
            #pragma unroll
            for (int b = 0; b < B; ++b){ float e = emb[b*TE + i]; semb[b][i] = e * sigmoidf_(e); }
        __syncthreads();
        int o = t & 15, p = t >> 4;
        int j = c*16 + o;
        float acc[B] = {0.f,0.f,0.f,0.f};
        for (int i = 0; i < 128; ++i){
            int e = p*128 + i;
            float wv = emb_W[(size_t)e*1024 + j];
            #pragma unroll
            for (int b = 0; b < B; ++b) acc[b] += semb[b][e] * wv;
        }
        #pragma unroll
        for (int b = 0; b < B; ++b) red[p][b*16 + o] = acc[b];
        __syncthreads();
        if (t < 64){
            int b = t >> 4, o2 = t & 15;
            int j2 = c*16 + o2;
            float s = 0.f;
            #pragma unroll
            for (int pp = 0; pp < 16; ++pp) s += red[pp][b*16 + o2];
            ss[b*1024 + j2] = s + emb_b[j2];
        }
    }
}

// ======== k_att: attn state only, 512 threads (halved per-thread dot) ========
__global__ __launch_bounds__(512) void k_att(const bf16* __restrict__ kbuf,
                                             const bf16* __restrict__ vbuf,
                                             bf16* __restrict__ attF){
    __shared__ float kh[NN*DH];          // 64 KB
    __shared__ float vh[NN*DH];          // 64 KB
    __shared__ float pm[8][DH], ps[8][DH];
    int t = threadIdx.x, h = blockIdx.x, b = blockIdx.y;
    for (int k = 0; k < NN*DH/512; ++k){
        int m = k*512 + t;
        int n = m >> 6, dl = m & 63;
        size_t src = (size_t)(b*NN + n)*D + h*DH + dl;
        kh[m] = (float)kbuf[src]; vh[m] = (float)vbuf[src];
    }
    __syncthreads();
    int d = t & 63, c = t >> 6;            // 8 chunks of 32 tokens
    float mx = -1e30f;
    for (int n = c*32; n < c*32+32; ++n) mx = fmaxf(mx, kh[n*DH + d]);
    pm[c][d] = mx;
    __syncthreads();
    mx = pm[0][d];
    #pragma unroll
    for (int cc = 1; cc < 8; ++cc) mx = fmaxf(mx, pm[cc][d]);
    float s = 0.f;
    for (int n = c*32; n < c*32+32; ++n){ float e = __expf(kh[n*DH + d] - mx); kh[n*DH + d] = e; s += e; }
    ps[c][d] = s;
    __syncthreads();
    float sden = ps[0][d];
    #pragma unroll
    for (int cc = 1; cc < 8; ++cc) sden += ps[cc][d];
    float inv = 1.f/sden;
    for (int n = c*32; n < c*32+32; ++n) kh[n*DH + d] *= inv;
    __syncthreads();
    int dl = t >> 3, dd0 = (t & 7)*8;      // 8 outputs per thread
    float acc[8];
    #pragma unroll
    for (int i = 0; i < 8; ++i) acc[i] = 0.f;
    for (int n = 0; n < NN; ++n){
        float vv = vh[n*DH + dl];
        #pragma unroll
        for (int i = 0; i < 8; ++i) acc[i] += kh[n*DH + dd0 + i] * vv;
    }
    // fragment-ordered write: contents att[dl][dd0..dd0+7]
    size_t hbase = ((size_t)(b*H + h)) << 12;
    int f  = (dl >> 4)*2 + (dd0 >> 5);
    int ln = ((dd0 >> 3) & 3)*16 + (dl & 15);
    bf16x8 ov;
    #pragma unroll
    for (int j = 0; j < 8; ++j) ov[j] = (bf16)acc[j];
    *(bf16x8*)&attF[hbase + f*512 + ln*8] = ov;
}

// ======== rolled, register-double-buffered GEMM over K=512 (+T5 setprio) — r10 exact ========
__device__ __forceinline__ void gemm_body(const bf16* __restrict__ wfrag,
                                          const bf16* __restrict__ afrag,
                                          f32x4 (&acc)[4][4]){
    bf16x8 b0[4], b1[4];
    #pragma unroll
    for (int nt = 0; nt < 4; ++nt) b0[nt] = *(const bf16x8*)&wfrag[nt*512];
    #pragma unroll
    for (int nt = 0; nt < 4; ++nt) b1[nt] = *(const bf16x8*)&wfrag[SLICE + nt*512];
    const bf16* wp = wfrag + 2*(size_t)SLICE;
    const bf16* ap = afrag;
    __builtin_amdgcn_s_setprio(1);
    for (int kk = 0; kk < 14; kk += 2){
        bf16x8 aa[4];
        #pragma unroll
        for (int mt = 0; mt < 4; ++mt) aa[mt] = *(const bf16x8*)&ap[mt*16*AS];
        #pragma unroll
        for (int nt = 0; nt < 4; ++nt)
            #pragma unroll
            for (int mt = 0; mt < 4; ++mt)
                acc[mt][nt] = __builtin_amdgcn_mfma_f32_16x16x32_bf16(aa[mt], b0[nt], acc[mt][nt], 0, 0, 0);
        #pragma unroll
        for (int nt = 0; nt < 4; ++nt) b0[nt] = *(const bf16x8*)&wp[nt*512];
        #pragma unroll
        for (int mt = 0; mt < 4; ++mt) aa[mt] = *(const bf16x8*)&ap[mt*16*AS + 32];
        #pragma unroll
        for (int nt = 0; nt < 4; ++nt)
            #pragma unroll
            for (int mt = 0; mt < 4; ++mt)
                acc[mt][nt] = __builtin_amdgcn_mfma_f32_16x16x32_bf16(aa[mt], b1[nt], acc[mt][nt], 0, 0, 0);
        #pragma unroll
        for (int nt = 0; nt < 4; ++nt) b1[nt] = *(const bf16x8*)&wp[SLICE + nt*512];
        wp += 2*(size_t)SLICE; ap += 64;
    }
    {
        bf16x8 aa[4];
        #pragma unroll
        for (int mt = 0; mt < 4; ++mt) aa[mt] = *(const bf16x8*)&ap[mt*16*AS];
        #pragma unroll
        for (int nt = 0; nt < 4; ++nt)
            #pragma unroll
            for (int mt = 0; mt < 4; ++mt)
                acc[mt][nt] = __builtin_amdgcn_mfma_f32_16x16x32_bf16(aa[mt], b0[nt], acc[mt][nt], 0, 0, 0);
        #pragma unroll
        for (int mt = 0; mt < 4; ++mt) aa[mt] = *(const bf16x8*)&ap[mt*16*AS + 32];
        #pragma unroll
        for (int nt = 0; nt < 4; ++nt)
            #pragma unroll
            for (int mt = 0; mt < 4; ++mt)
                acc[mt][nt] = __builtin_amdgcn_mfma_f32_16x16x32_bf16(aa[mt], b1[nt], acc[mt][nt], 0, 0, 0);
    }
    __builtin_amdgcn_s_setprio(0);
}

// ======== main fused kernel: 64 rows/block, 8 waves (1 head each), 2 blocks/CU — r10 exact ========
__global__ __launch_bounds__(512, 4) void k_main(
    const float* __restrict__ x, const bf16* __restrict__ WqS, const float* __restrict__ bq,
    const float* __restrict__ lg, const float* __restrict__ lb,
    const bf16* __restrict__ attF, const float* __restrict__ ssb,
    const float* __restrict__ sg, const float* __restrict__ sb,
    const bf16* __restrict__ oWS, const float* __restrict__ ob,
    float* __restrict__ out){
    __shared__ __align__(16) bf16 Abuf[MR*AS];      // 66.6 KB: LN(x) -> q -> silu(h) -> f32 scratch
    __shared__ float st_s[MR][8];
    __shared__ float st_q[MR][8];
    const int t = threadIdx.x, w = t >> 6, lane = t & 63;
    const int l15 = lane & 15, grp = lane >> 4;
    const long g0 = (long)blockIdx.x * MR;
    const int b = (int)(g0 / T);
    const int wb = w * 64;
    const size_t fragoff = (size_t)w*2048 + (size_t)l15*32 + (size_t)grp*8;

    // ---- phase A: LN(x) -> Abuf bf16 (8 rows per wave, rolled)
    {
        float4 lg0 = *(const float4*)&lg[lane*8], lg1 = *(const float4*)&lg[lane*8+4];
        float4 lb0 = *(const float4*)&lb[lane*8], lb1 = *(const float4*)&lb[lane*8+4];
        #pragma unroll 2
        for (int rr = 0; rr < 8; ++rr){
            int r = w*8 + rr;
            const float* xp = &x[(size_t)(g0 + r)*D + lane*8];
            float4 v0 = *(const float4*)xp, v1 = *(const float4*)(xp+4);
            float s  = v0.x+v0.y+v0.z+v0.w + v1.x+v1.y+v1.z+v1.w;
            float sq = v0.x*v0.x+v0.y*v0.y+v0.z*v0.z+v0.w*v0.w
                     + v1.x*v1.x+v1.y*v1.y+v1.z*v1.z+v1.w*v1.w;
            #pragma unroll
            for (int o = 32; o; o >>= 1){ s += __shfl_xor(s,o); sq += __shfl_xor(sq,o); }
            float m = s*(1.f/D), var = sq*(1.f/D) - m*m, rstd = rsqrtf(var + 1e-5f);
            bf16x8 ov;
            ov[0] = (bf16)((v0.x-m)*rstd*lg0.x + lb0.x);
            ov[1] = (bf16)((v0.y-m)*rstd*lg0.y + lb0.y);
            ov[2] = (bf16)((v0.z-m)*rstd*lg0.z + lb0.z);
            ov[3] = (bf16)((v0.w-m)*rstd*lg0.w + lb0.w);
            ov[4] = (bf16)((v1.x-m)*rstd*lg1.x + lb1.x);
            ov[5] = (bf16)((v1.y-m)*rstd*lg1.y + lb1.y);
            ov[6] = (bf16)((v1.z-m)*rstd*lg1.z + lb1.z);
            ov[7] = (bf16)((v1.w-m)*rstd*lg1.w + lb1.w);
            *(bf16x8*)&Abuf[r*AS + lane*8] = ov;
        }
    }
    __syncthreads();

    // ---- GEMM1: q = LN(x) @ Wq
    f32x4 acc[4][4];
    #pragma unroll
    for (int mt = 0; mt < 4; ++mt)
        #pragma unroll
        for (int nt = 0; nt < 4; ++nt) acc[mt][nt] = (f32x4){0.f,0.f,0.f,0.f};
    gemm_body(WqS + fragoff, &Abuf[l15*AS + grp*8], acc);

    // ---- attF prefetch (L2) — lands during softmax, consumed in phase D
    bf16x8 bfr[2][4];
    {
        const bf16* ab = attF + (((size_t)b*H + w) << 12);
        #pragma unroll
        for (int ks = 0; ks < 2; ++ks)
            #pragma unroll
            for (int n4 = 0; n4 < 4; ++n4)
                bfr[ks][n4] = *(const bf16x8*)&ab[(n4*2 + ks)*512 + lane*8];
    }

    // ---- softmax over this wave's head (in-register)
    {
        float bqv[4];
        #pragma unroll
        for (int nt = 0; nt < 4; ++nt) bqv[nt] = bq[wb + nt*16 + l15];
        #pragma unroll
        for (int mt = 0; mt < 4; ++mt)
            #pragma unroll
            for (int r = 0; r < 4; ++r){
                float v0 = acc[mt][0][r] + bqv[0];
                float v1 = acc[mt][1][r] + bqv[1];
                float v2 = acc[mt][2][r] + bqv[2];
                float v3 = acc[mt][3][r] + bqv[3];
                float mx = fmaxf(fmaxf(v0,v1), fmaxf(v2,v3));
                #pragma unroll
                for (int o = 1; o < 16; o <<= 1) mx = fmaxf(mx, __shfl_xor(mx, o));
                float e0 = __expf(v0-mx), e1 = __expf(v1-mx), e2 = __expf(v2-mx), e3 = __expf(v3-mx);
                float sden = e0+e1+e2+e3;
                #pragma unroll
                for (int o = 1; o < 16; o <<= 1) sden += __shfl_xor(sden, o);
                float inv = 1.f/sden;
                acc[mt][0][r] = e0*inv; acc[mt][1][r] = e1*inv;
                acc[mt][2][r] = e2*inv; acc[mt][3][r] = e3*inv;
            }
    }
    __syncthreads();   // all waves done reading Abuf (A of GEMM1) before overwrite

    // q (bf16) -> Abuf [all 64 rows][own 64 cols] — wave-local region
    #pragma unroll
    for (int mt = 0; mt < 4; ++mt)
        #pragma unroll
        for (int nt = 0; nt < 4; ++nt)
            #pragma unroll
            for (int r = 0; r < 4; ++r)
                Abuf[(mt*16 + grp*4 + r)*AS + wb + nt*16 + l15] = (bf16)acc[mt][nt][r];
    // wave-local write->read: LDS wait + scheduling fence (rule #18), no block barrier
    asm volatile("s_waitcnt lgkmcnt(0)" ::: "memory");
    __builtin_amdgcn_sched_barrier(0);

    // ---- phase D: y = q @ att[head w]  (B already in registers)
    #pragma unroll
    for (int mt = 0; mt < 4; ++mt)
        #pragma unroll
        for (int nt = 0; nt < 4; ++nt) acc[mt][nt] = (f32x4){0.f,0.f,0.f,0.f};
    #pragma unroll
    for (int ks = 0; ks < 2; ++ks){
        bf16x8 qa[4];
        #pragma unroll
        for (int mt = 0; mt < 4; ++mt)
            qa[mt] = *(const bf16x8*)&Abuf[(mt*16 + l15)*AS + wb + ks*32 + grp*8];
        #pragma unroll
        for (int n4 = 0; n4 < 4; ++n4)
            #pragma unroll
            for (int mt = 0; mt < 4; ++mt)
                acc[mt][n4] = __builtin_amdgcn_mfma_f32_16x16x32_bf16(qa[mt], bfr[ks][n4], acc[mt][n4], 0, 0, 0);
    }

    // ---- LN(y) stats: per-wave partials -> LDS -> combine
    #pragma unroll
    for (int mt = 0; mt < 4; ++mt)
        #pragma unroll
        for (int r = 0; r < 4; ++r){
            float s = 0.f, q2 = 0.f;
            #pragma unroll
            for (int nt = 0; nt < 4; ++nt){ float v = acc[mt][nt][r]; s += v; q2 += v*v; }
            #pragma unroll
            for (int o = 1; o < 16; o <<= 1){ s += __shfl_xor(s, o); q2 += __shfl_xor(q2, o); }
            if (l15 == 0){ st_s[mt*16 + grp*4 + r][w] = s; st_q[mt*16 + grp*4 + r][w] = q2; }
        }
    __syncthreads();

    // ---- stylize + silu -> Abuf bf16
    {
        float sgv[4], sbv[4], sscv[4], sshv[4];
        #pragma unroll
        for (int nt = 0; nt < 4; ++nt){
            int col = wb + nt*16 + l15;
            sgv[nt] = sg[col]; sbv[nt] = sb[col];
            sscv[nt] = ssb[b*1024 + col]; sshv[nt] = ssb[b*1024 + 512 + col];
        }
        #pragma unroll
        for (int mt = 0; mt < 4; ++mt)
            #pragma unroll
            for (int r = 0; r < 4; ++r){
                int row = mt*16 + grp*4 + r;
                float4 s0 = *(const float4*)&st_s[row][0];
                float4 s1 = *(const float4*)&st_s[row][4];
                float4 q0 = *(const float4*)&st_q[row][0];
                float4 q1 = *(const float4*)&st_q[row][4];
                float m = (s0.x+s0.y+s0.z+s0.w + s1.x+s1.y+s1.z+s1.w)*(1.f/D);
                float var = (q0.x+q0.y+q0.z+q0.w + q1.x+q1.y+q1.z+q1.w)*(1.f/D) - m*m;
                float rstd = rsqrtf(var + 1e-5f);
                #pragma unroll
                for (int nt = 0; nt < 4; ++nt){
                    float yn = (acc[mt][nt][r] - m)*rstd*sgv[nt] + sbv[nt];
                    float h2 = yn*(1.f + sscv[nt]) + sshv[nt];
                    Abuf[row*AS + wb + nt*16 + l15] = (bf16)(h2 * sigmoidf_(h2));
                }
            }
    }
    __syncthreads();   // h complete across all waves before GEMM2 reads full K

    // ---- GEMM2: out_pre = silu(h) @ out_W
    #pragma unroll
    for (int mt = 0; mt < 4; ++mt)
        #pragma unroll
        for (int nt = 0; nt < 4; ++nt) acc[mt][nt] = (f32x4){0.f,0.f,0.f,0.f};
    gemm_body(oWS + fragoff, &Abuf[l15*AS + grp*8], acc);

    // ---- epilogue: LDS-bounce transpose -> coalesced (acc + ob + x) stores
    float* scr = (float*)Abuf;              // 32 rows x stride 516 f32 (66048B <= 66560B)
    #pragma unroll
    for (int half = 0; half < 2; ++half){
        __syncthreads();    // half0: all GEMM2 LDS reads done; half1: prev flush reads done
        #pragma unroll
        for (int mt2 = 0; mt2 < 2; ++mt2){
            int mt = half*2 + mt2;
            #pragma unroll
            for (int nt = 0; nt < 4; ++nt)
                #pragma unroll
                for (int r = 0; r < 4; ++r)
                    scr[(mt2*16 + grp*4 + r)*516 + wb + nt*16 + l15] = acc[mt][nt][r];
        }
        __syncthreads();
        #pragma unroll 2
        for (int i = 0; i < 8; ++i){
            int c = i*512 + t;
            int row = c >> 7, col4 = (c & 127) << 2;
            float4 v  = *(const float4*)&scr[row*516 + col4];
            size_t gi = (size_t)(g0 + half*32 + row)*D + col4;
            float4 xb = *(const float4*)&x[gi];
            float4 o4 = *(const float4*)&ob[col4];
            float4 r4 = {v.x+o4.x+xb.x, v.y+o4.y+xb.y, v.z+o4.z+xb.z, v.w+o4.w+xb.w};
            *(float4*)&out[gi] = r4;
        }
    }
}

extern "C" void kernel_launch(void* const* d_in, const int* in_sizes, int n_in,
                              void* d_out, int out_size, void* d_ws, size_t ws_size,
                              hipStream_t stream){
    const float* x     = (const float*)d_in[0];
    const float* xf    = (const float*)d_in[1];
    const float* emb   = (const float*)d_in[2];
    const float* Wq    = (const float*)d_in[3];
    const float* bq    = (const float*)d_in[4];
    const float* Wk    = (const float*)d_in[5];
    const float* bk    = (const float*)d_in[6];
    const float* Wv    = (const float*)d_in[7];
    const float* bv    = (const float*)d_in[8];
    const float* ln_g  = (const float*)d_in[9];
    const float* ln_b  = (const float*)d_in[10];
    const float* tln_g = (const float*)d_in[11];
    const float* tln_b = (const float*)d_in[12];
    const float* emb_W = (const float*)d_in[13];
    const float* emb_b = (const float*)d_in[14];
    const float* sn_g  = (const float*)d_in[15];
    const float* sn_b  = (const float*)d_in[16];
    const float* out_W = (const float*)d_in[17];
    const float* out_b = (const float*)d_in[18];
    float* out = (float*)d_out;

    // workspace carve
    float* ssb  = (float*)d_ws;                          // B*1024 f32
    bf16*  kbuf = (bf16*)(ssb + B*1024);                 // B*NN*D bf16
    bf16*  vbuf = kbuf + (size_t)B*NN*D;                 // B*NN*D bf16
    bf16*  attF = vbuf + (size_t)B*NN*D;                 // B*H*DH*DH bf16
    bf16*  wqS  = attF + (size_t)B*H*DH*DH;              // D*D bf16 (staged layout)
    bf16*  owS  = wqS  + (size_t)D*D;                    // D*D bf16

    k_prep_all<<<dim3(704), dim3(256), 0, stream>>>(xf, Wk, bk, Wv, bv, tln_g, tln_b, kbuf, vbuf,
                                                    Wq, out_W, wqS, owS,
                                                    emb, emb_W, emb_b, ssb);
    k_att     <<<dim3(H, B), dim3(512), 0, stream>>>(kbuf, vbuf, attF);
    k_main    <<<dim3(B*T/MR), dim3(512), 0, stream>>>(x, wqS, bq, ln_g, ln_b, attF, ssb,
                                                       sn_g, sn_b, owS, out_b, out);
}